// Round 1
// baseline (373.604 us; speedup 1.0000x reference)
//
#include <hip/hip_runtime.h>
#include <math.h>

typedef _Float16 f16;
typedef _Float16 half8 __attribute__((ext_vector_type(8)));
typedef _Float16 half4v __attribute__((ext_vector_type(4)));
typedef _Float16 half2v __attribute__((ext_vector_type(2)));
typedef float floatx4 __attribute__((ext_vector_type(4)));
typedef unsigned int u32;

#define AS1 __attribute__((address_space(1)))
#define AS3 __attribute__((address_space(3)))

// async global->LDS, 16B per lane; LDS dest is wave-uniform base + lane*16.
__device__ __forceinline__ void stage16(f16* l, const f16* g) {
    __builtin_amdgcn_global_load_lds((const AS1 u32*)g, (AS3 u32*)l, 16, 0, 0);
}

__device__ __forceinline__ void barrier_mem() {
    asm volatile("" ::: "memory");
    __builtin_amdgcn_s_barrier();
    asm volatile("" ::: "memory");
}

// ---------------- f32 -> f16 convert ----------------
__global__ __launch_bounds__(256) void cvt_f32_f16(const float* __restrict__ in,
                                                   f16* __restrict__ out, int n4) {
    int i = blockIdx.x * blockDim.x + threadIdx.x;
    if (i >= n4) return;
    float4 v = ((const float4*)in)[i];
    half4v h = {(f16)v.x, (f16)v.y, (f16)v.z, (f16)v.w};
    ((half4v*)out)[i] = h;
}

// ---------------- 256x256 8-phase NT GEMM: C[M,N] = A[M,K]*B[N,K]^T + bias ----------------
// 8 waves (2M x 4N), BK=64 split into two 32-k-slices. LDS 128 KiB:
// sm[buf][quarter][8192], quarter: 0=A_k0 1=A_k1 2=B_k0 3=B_k1 (16 KiB each).
// In-row chunk rotation swizzle (phys = (logical + row>>1)&3) applied via
// pre-swizzled global source; frag ds_read_b128 lands 2-way (free) on banks.
// Counted vmcnt(6) at tile entry: 3 quarters (6 loads) stay in flight across
// the barrier; vmcnt(0) only for the last K-tile.
constexpr int GK = 1280;
constexpr int KT = 20;   // 1280 / 64

__device__ __forceinline__ void stage_q(const f16* __restrict__ g, f16* l, int t) {
#pragma unroll
    for (int u = 0; u < 2; u++) {
        const int c = t + u * 512;          // chunk 0..1023 (16B each)
        const int row = c >> 2;             // 0..255
        const int lc = ((c & 3) - (row >> 1)) & 3;   // logical chunk for this phys slot
        stage16(l + c * 8, g + (size_t)row * GK + lc * 8);
    }
}

#define MMA_CLUSTER(AF, BF, MB)                                               \
    asm volatile("s_waitcnt lgkmcnt(0)" ::: "memory");                        \
    __builtin_amdgcn_s_setprio(1);                                            \
    _Pragma("unroll")                                                         \
    for (int m_ = 0; m_ < 4; m_++) {                                          \
        _Pragma("unroll")                                                     \
        for (int n_ = 0; n_ < 4; n_++)                                        \
            acc[MB + m_][n_] = __builtin_amdgcn_mfma_f32_16x16x32_f16(        \
                AF[m_], BF[n_], acc[MB + m_][n_], 0, 0, 0);                   \
    }                                                                         \
    __builtin_amdgcn_s_setprio(0);

__global__ __launch_bounds__(512, 2) void gemm256(const f16* __restrict__ A,
                                                  const f16* __restrict__ B,
                                                  const float* __restrict__ bias,
                                                  f16* __restrict__ outH,
                                                  float* __restrict__ outF,
                                                  int N, int NT) {
    __shared__ f16 sm[2][4][8192];   // 128 KiB
    const int t = threadIdx.x;
    const int lane = t & 63, w = t >> 6;
    const int wm = w >> 2, wn = w & 3;          // 2M x 4N waves
    const int c16 = lane & 15, quad = lane >> 4;
    // XCD-aware swizzle (grid % 8 == 0 for both launches): per-XCD contiguous
    // gid range = contiguous bm rows -> A panels L2-resident per XCD.
    const int id = blockIdx.x;
    const int nx = (int)gridDim.x >> 3;
    const int gid = (id & 7) * nx + (id >> 3);
    const int bm = gid / NT, bn = gid % NT;
    const f16* Ab = A + (size_t)bm * 256 * GK;
    const f16* Bb = B + (size_t)bn * 256 * GK;

    floatx4 acc[8][4] = {};

    auto rdA = [&](const f16* q, int mh, half8(&af)[4]) {
#pragma unroll
        for (int m = 0; m < 4; m++) {
            const int r = wm * 128 + mh * 64 + m * 16 + c16;
            af[m] = *(const half8*)(q + r * 32 + (((quad + (r >> 1)) & 3) * 8));
        }
    };
    auto rdB = [&](const f16* q, half8(&bf)[4]) {
#pragma unroll
        for (int n = 0; n < 4; n++) {
            const int r = wn * 64 + n * 16 + c16;
            bf[n] = *(const half8*)(q + r * 32 + (((quad + (r >> 1)) & 3) * 8));
        }
    };

    // Prologue: tile0 all 4 quarters + tile1's first 3 quarters (stream order
    // matters for in-order vmcnt retirement; fence each quarter).
    stage_q(Bb + 0,  &sm[0][2][0], t); asm volatile("" ::: "memory");  // B_k0(0)
    stage_q(Ab + 0,  &sm[0][0][0], t); asm volatile("" ::: "memory");  // A_k0(0)
    stage_q(Bb + 32, &sm[0][3][0], t); asm volatile("" ::: "memory");  // B_k1(0)
    stage_q(Ab + 32, &sm[0][1][0], t); asm volatile("" ::: "memory");  // A_k1(0)
    stage_q(Bb + 64, &sm[1][2][0], t); asm volatile("" ::: "memory");  // B_k0(1)
    stage_q(Ab + 64, &sm[1][0][0], t); asm volatile("" ::: "memory");  // A_k0(1)
    stage_q(Bb + 96, &sm[1][3][0], t); asm volatile("" ::: "memory");  // B_k1(1)
    // A_k1(1) is staged at tile0's P0 (its slot in buf1 needs no earlier owner).

    for (int kt = 0; kt < KT; kt++) {
        const int p = kt & 1;
        const f16* qA0 = &sm[p][0][0];
        const f16* qA1 = &sm[p][1][0];
        const f16* qB0 = &sm[p][2][0];
        const f16* qB1 = &sm[p][3][0];
        // Tile entry: this tile's 4 quarters retired; next tile's 3 newest
        // quarters (6 loads) stay in flight. Last tile: full drain.
        if (kt == KT - 1) { asm volatile("s_waitcnt vmcnt(0)" ::: "memory"); }
        else              { asm volatile("s_waitcnt vmcnt(6)" ::: "memory"); }
        barrier_mem();

        half8 af[4], bf0[4], bf1[4];
        // ---- P0: ks=0, m-half 0.  Stage A_k1(kt+1) -> other buffer.
        rdB(qB0, bf0);
        rdA(qA0, 0, af);
        if (kt + 1 < KT) stage_q(Ab + (size_t)(kt + 1) * 64 + 32, &sm[p ^ 1][1][0], t);
        barrier_mem();
        MMA_CLUSTER(af, bf0, 0);
        barrier_mem();
        // ---- P1: ks=0, m-half 1 (bf0 reused).  Stage B_k0(kt+2) -> this buffer
        // (its last read was P0, barrier crossed).
        rdA(qA0, 1, af);
        if (kt + 2 < KT) stage_q(Bb + (size_t)(kt + 2) * 64, &sm[p][2][0], t);
        barrier_mem();
        MMA_CLUSTER(af, bf0, 4);
        barrier_mem();
        // ---- P2: ks=1, m-half 0.  Stage A_k0(kt+2) (last read was P1).
        rdB(qB1, bf1);
        rdA(qA1, 0, af);
        if (kt + 2 < KT) stage_q(Ab + (size_t)(kt + 2) * 64, &sm[p][0][0], t);
        barrier_mem();
        MMA_CLUSTER(af, bf1, 0);
        barrier_mem();
        // ---- P3: ks=1, m-half 1 (bf1 reused).  Stage B_k1(kt+2) (last read P2).
        rdA(qA1, 1, af);
        if (kt + 2 < KT) stage_q(Bb + (size_t)(kt + 2) * 64 + 32, &sm[p][3][0], t);
        barrier_mem();
        MMA_CLUSTER(af, bf1, 4);
        barrier_mem();
    }

    // Epilogue: same C/D mapping as before (row = A-side + quad*4 + r, col = B-side + c16).
    const int colBase = bn * 256 + wn * 64;
    const size_t rowBase = (size_t)bm * 256 + wm * 128;
#pragma unroll
    for (int n = 0; n < 4; n++) {
        const int col = colBase + n * 16 + c16;
        const float bv = bias[col];
#pragma unroll
        for (int m = 0; m < 8; m++) {
            const size_t row = rowBase + m * 16 + quad * 4;
#pragma unroll
            for (int r = 0; r < 4; r++) {
                const float v = acc[m][n][r] + bv;
                if (outH) outH[(row + r) * (size_t)N + col] = (f16)v;
                else      outF[(row + r) * (size_t)N + col] = v;
            }
        }
    }
}

// ---------------- RoPE + layout: qkv[S,3840] -> QB/KB [H][S][96], VT [H*80][S] ----------------
#define QSCALE (0.11180339887498949f * 1.4426950408889634f)

__global__ __launch_bounds__(320) void rope_kernel(const f16* __restrict__ qkv,
                                                   const float* __restrict__ cosp,
                                                   const float* __restrict__ sinp,
                                                   f16* __restrict__ qb, f16* __restrict__ kb,
                                                   f16* __restrict__ vt) {
    constexpr int S = 8192;
    const int bs = blockIdx.x, h = blockIdx.y, t = threadIdx.x;
    const int sl = t / 5, g = t % 5;   // 64 s-rows x 5 groups of 8 d-pairs
    const int s = bs * 64 + sl;
    {
        const size_t base = (size_t)s * 3840 + h * 80 + g * 8;
        half8 qa = *(const half8*)(qkv + base);
        half8 qc = *(const half8*)(qkv + base + 40);
        half8 ka = *(const half8*)(qkv + base + 1280);
        half8 kc = *(const half8*)(qkv + base + 1320);
        const float* cp = cosp + (size_t)s * 80 + g * 8;
        const float* sp = sinp + (size_t)s * 80 + g * 8;
        half8 qo0, qo1, ko0, ko1;
#pragma unroll
        for (int j = 0; j < 8; j++) {
            float c0 = cp[j], c1 = cp[j + 40];
            float n0 = sp[j], n1 = sp[j + 40];
            float q0 = (float)qa[j], q1 = (float)qc[j];
            float k0 = (float)ka[j], k1 = (float)kc[j];
            qo0[j] = (f16)((q0 * c0 - q1 * n0) * QSCALE);
            qo1[j] = (f16)((q1 * c1 + q0 * n1) * QSCALE);
            ko0[j] = (f16)(k0 * c0 - k1 * n0);
            ko1[j] = (f16)(k1 * c1 + k0 * n1);
        }
        const size_t ob = ((size_t)h * S + s) * 96 + g * 8;
        *(half8*)(qb + ob)      = qo0;
        *(half8*)(qb + ob + 40) = qo1;
        *(half8*)(kb + ob)      = ko0;
        *(half8*)(kb + ob + 40) = ko1;
        if (g < 2) {  // pads 80..95
            half8 qp = {}, kp = {};
            if (g == 0) { qp[0] = (f16)(-8.0f); kp[0] = (f16)(1.0f); }
            const size_t pb = ((size_t)h * S + s) * 96 + 80 + g * 8;
            *(half8*)(qb + pb) = qp;
            *(half8*)(kb + pb) = kp;
        }
    }
    // v transpose via LDS: [64 s][80 d] -> VT[h*80+d][s]
    __shared__ f16 vls[64][81];
    for (int j = t; j < 64 * 80; j += 320) {
        int s2 = j / 80, d = j % 80;
        vls[s2][d] = qkv[((size_t)(bs * 64 + s2)) * 3840 + 2560 + h * 80 + d];
    }
    __syncthreads();
    for (int j = t; j < 64 * 80; j += 320) {
        int d = j >> 6, s2 = j & 63;
        vt[((size_t)(h * 80 + d)) * S + bs * 64 + s2] = vls[s2][d];
    }
}

// ---------------- flash attention: 256 q rows/block, XCD-swizzled grid ----------------
__global__ __launch_bounds__(256, 2) void attn_kernel(const f16* __restrict__ qb,
                                                      const f16* __restrict__ kb,
                                                      const f16* __restrict__ vt,
                                                      const int* __restrict__ cu,
                                                      f16* __restrict__ out) {
    constexpr int S = 8192;
    __shared__ f16 Ks[2][64 * 96];   // 24576 B (double-buffered, swizzled)
    __shared__ f16 Ps[256 * 72];     // 36864 B (wave-private 64-q slabs)
    const int t = threadIdx.x, lane = t & 63, w = t >> 6;
    const int c16 = lane & 15, quad = lane >> 4;
    const int id = blockIdx.x;
    const int pair = id & 127;
    const int qt = id >> 7;          // 0..3: which 256-row q tile
    const int h = pair & 15, z = pair >> 4;
    const int s0 = cu[z];

    half8 qf[4][3];
#pragma unroll
    for (int qt2 = 0; qt2 < 4; qt2++)
#pragma unroll
        for (int ks = 0; ks < 3; ks++)
            qf[qt2][ks] = *(const half8*)(qb + ((size_t)h * S + s0 + qt * 256 + w * 64 + qt2 * 16 + c16) * 96 + ks * 32 + quad * 8);

    const f16 ov = (c16 == 0) ? (f16)1.f : (f16)0.f;
    const half8 onesf = {ov, ov, ov, ov, ov, ov, ov, ov};

    const int sR = t >> 2;
    const int sK = ((t & 3) - (sR >> 1)) & 3;

    {   // stage K tile 0
        const f16* Kg = kb + ((size_t)h * S + s0) * 96;
#pragma unroll
        for (int j = 0; j < 3; j++)
            stage16(&Ks[0][0] + (j * 256 + t) * 8, Kg + (size_t)sR * 96 + j * 32 + sK * 8);
    }
    __syncthreads();

    floatx4 o[6][4] = {};   // O^T tiles [d-tile][q-subtile]; dt=5 row 80 = l

    for (int kv = 0; kv < 16; kv++) {
        if (kv < 15) {
            const f16* Kg = kb + ((size_t)h * S + s0 + (kv + 1) * 64) * 96;
            f16* Kd = &Ks[(kv + 1) & 1][0];
#pragma unroll
            for (int j = 0; j < 3; j++)
                stage16(Kd + (j * 256 + t) * 8, Kg + (size_t)sR * 96 + j * 32 + sK * 8);
        }
        const f16* Kc = &Ks[kv & 1][0];
        floatx4 sc[4][4] = {};
#pragma unroll
        for (int ks = 0; ks < 3; ks++) {
            half8 kf[4];
#pragma unroll
            for (int mt = 0; mt < 4; mt++) {
                const int row = mt * 16 + c16;
                kf[mt] = *(const half8*)(Kc + (ks * 256 + 4 * row + ((quad + (row >> 1)) & 3)) * 8);
            }
#pragma unroll
            for (int qt2 = 0; qt2 < 4; qt2++)
#pragma unroll
                for (int mt = 0; mt < 4; mt++)
                    sc[mt][qt2] = __builtin_amdgcn_mfma_f32_16x16x32_f16(kf[mt], qf[qt2][ks], sc[mt][qt2], 0, 0, 0);
        }
#pragma unroll
        for (int qt2 = 0; qt2 < 4; qt2++) {
            const int q = w * 64 + qt2 * 16 + c16;
#pragma unroll
            for (int mt = 0; mt < 4; mt++) {
                half4v pv;
#pragma unroll
                for (int r = 0; r < 4; r++)
                    pv[r] = (f16)__builtin_amdgcn_exp2f(sc[mt][qt2][r]);
                *(half4v*)(Ps + q * 72 + mt * 16 + quad * 4) = pv;
            }
        }
#pragma unroll
        for (int ks = 0; ks < 2; ks++) {
            const f16* Vg = vt + (size_t)h * 80 * S + s0 + kv * 64 + ks * 32;
            half8 vf[5];
#pragma unroll
            for (int dt = 0; dt < 5; dt++)
                vf[dt] = *(const half8*)(Vg + (size_t)(dt * 16 + c16) * S + quad * 8);
#pragma unroll
            for (int qt2 = 0; qt2 < 4; qt2++) {
                const int q = w * 64 + qt2 * 16 + c16;
                half8 pf = *(const half8*)(Ps + q * 72 + ks * 32 + quad * 8);
#pragma unroll
                for (int dt = 0; dt < 5; dt++)
                    o[dt][qt2] = __builtin_amdgcn_mfma_f32_16x16x32_f16(vf[dt], pf, o[dt][qt2], 0, 0, 0);
                o[5][qt2] = __builtin_amdgcn_mfma_f32_16x16x32_f16(onesf, pf, o[5][qt2], 0, 0, 0);
            }
        }
        __syncthreads();
    }
#pragma unroll
    for (int qt2 = 0; qt2 < 4; qt2++) {
        const float l = __shfl(o[5][qt2][0], c16);
        const float inv = 1.f / l;
        const size_t srow = (size_t)s0 + qt * 256 + w * 64 + qt2 * 16 + c16;
#pragma unroll
        for (int dt = 0; dt < 5; dt++)
#pragma unroll
            for (int rp = 0; rp < 2; rp++) {
                half2v hv = {(f16)(o[dt][qt2][rp * 2] * inv), (f16)(o[dt][qt2][rp * 2 + 1] * inv)};
                *(half2v*)(out + srow * 1280 + h * 80 + dt * 16 + quad * 4 + rp * 2) = hv;
            }
    }
}

// ---------------- launch ----------------
extern "C" void kernel_launch(void* const* d_in, const int* in_sizes, int n_in,
                              void* d_out, int out_size, void* d_ws, size_t ws_size,
                              hipStream_t stream) {
    const float* hidden = (const float*)d_in[0];
    const int* cu       = (const int*)d_in[1];
    const float* cosp   = (const float*)d_in[2];
    const float* sinp   = (const float*)d_in[3];
    const float* qkv_w  = (const float*)d_in[4];
    const float* qkv_b  = (const float*)d_in[5];
    const float* proj_w = (const float*)d_in[6];
    const float* proj_b = (const float*)d_in[7];
    float* out = (float*)d_out;

    constexpr size_t S = 8192, DIM = 1280, N3 = 3840;
    f16* A16   = (f16*)d_ws;
    f16* W16   = A16 + S * DIM;          // qkv_w f16 (plain row-major [3840][1280])
    f16* P16   = W16 + N3 * DIM;         // proj_w f16 (plain row-major [1280][1280])
    f16* QKV16 = P16 + DIM * DIM;
    f16* QB    = QKV16 + S * N3;
    f16* KB    = QB + (size_t)16 * S * 96;
    f16* VT    = KB + (size_t)16 * S * 96;
    f16* AT16  = A16;  // reuse: hidden-f16 dead after QKV GEMM

    {
        int n4 = (int)(S * DIM / 4);
        cvt_f32_f16<<<(n4 + 255) / 256, 256, 0, stream>>>(hidden, A16, n4);
    }
    {
        int n4 = (int)(N3 * DIM / 4);
        cvt_f32_f16<<<(n4 + 255) / 256, 256, 0, stream>>>(qkv_w, W16, n4);
    }
    {
        int n4 = (int)(DIM * DIM / 4);
        cvt_f32_f16<<<(n4 + 255) / 256, 256, 0, stream>>>(proj_w, P16, n4);
    }
    gemm256<<<32 * 15, 512, 0, stream>>>(A16, W16, qkv_b, QKV16, nullptr, 3840, 15);
    rope_kernel<<<dim3(128, 16), 320, 0, stream>>>(QKV16, cosp, sinp, QB, KB, VT);
    attn_kernel<<<512, 256, 0, stream>>>(QB, KB, VT, cu, A16);
    gemm256<<<32 * 5, 512, 0, stream>>>(AT16, P16, proj_b, nullptr, out, 1280, 5);
}